// Round 1
// baseline (1903.320 us; speedup 1.0000x reference)
//
#include <hip/hip_runtime.h>
#include <stdint.h>

#define B_SZ   4
#define S_LEN  2048
#define D_MOD  1024
#define NH     16
#define DEPTH  64

typedef __attribute__((ext_vector_type(8))) __bf16 bfrag;
typedef __attribute__((ext_vector_type(4))) float  f32x4;
typedef __attribute__((ext_vector_type(4))) unsigned short u16x4;
typedef __attribute__((ext_vector_type(8))) unsigned short u16x8;

__device__ __forceinline__ unsigned short f2bf(float x) {
  unsigned u = __builtin_bit_cast(unsigned, x);
  u += 0x7fffu + ((u >> 16) & 1u);               // RNE
  return (unsigned short)(u >> 16);
}
__device__ __forceinline__ float bf2f(unsigned short h) {
  unsigned u = ((unsigned)h) << 16;
  return __builtin_bit_cast(float, u);
}
__device__ __forceinline__ float fexp2(float x) {
#if __has_builtin(__builtin_amdgcn_exp2f)
  return __builtin_amdgcn_exp2f(x);
#else
  return exp2f(x);
#endif
}
__device__ __forceinline__ void gload16(const unsigned short* g, unsigned short* l) {
  __builtin_amdgcn_global_load_lds(
      (const __attribute__((address_space(1))) unsigned int*)g,
      (__attribute__((address_space(3))) unsigned int*)l, 16, 0, 0);
}

// ---------------------------------------------------------------- cast fp32->bf16
__global__ __launch_bounds__(256) void cast_kernel(const float* __restrict__ x,
                                                   unsigned short* __restrict__ y, int n8) {
  int i = blockIdx.x * 256 + threadIdx.x;
  if (i >= n8) return;
  const f32x4* xp = (const f32x4*)x;
  f32x4 a = xp[i * 2], b = xp[i * 2 + 1];
  u16x8 o;
  o[0] = f2bf(a[0]); o[1] = f2bf(a[1]); o[2] = f2bf(a[2]); o[3] = f2bf(a[3]);
  o[4] = f2bf(b[0]); o[5] = f2bf(b[1]); o[6] = f2bf(b[2]); o[7] = f2bf(b[3]);
  *(u16x8*)(y + (size_t)i * 8) = o;
}

// ------------------------------------------- weight transpose+cast: Wt[n][k] = W[k][n]
__global__ __launch_bounds__(256) void wtrans_kernel(const float* __restrict__ W,
                                                     unsigned short* __restrict__ Wt) {
  __shared__ float tile[32][33];
  int bx = blockIdx.x * 32, by = blockIdx.y * 32;
  int tx = threadIdx.x, ty = threadIdx.y;  // 32 x 8
#pragma unroll
  for (int i = 0; i < 32; i += 8)
    tile[ty + i][tx] = W[(size_t)(by + ty + i) * D_MOD + bx + tx];
  __syncthreads();
#pragma unroll
  for (int i = 0; i < 32; i += 8)
    Wt[(size_t)(bx + ty + i) * D_MOD + by + tx] = f2bf(tile[tx][ty + i]);
}

// ---------------------------------------------------------------- GEMM: C = A @ B^T
// A[M][K] bf16 row-major, B[N][K] bf16 row-major ("bt" layout). 128x128 tile, BK=32.
// MODE 0: +bias[n], bf16 out in head-major [b][h][s][d]   (Q/K projections)
// MODE 1: +bias[m], bf16 out row-major [M][N] (+z strides) (V projection, transposed)
// MODE 2: +bias[n], fp32 out row-major [M][N]              (output projection)
template <int MODE>
__global__ __launch_bounds__(256) void gemm_bt(const unsigned short* __restrict__ A,
                                               const unsigned short* __restrict__ B,
                                               const float* __restrict__ bias,
                                               void* __restrict__ Cout,
                                               int N, int K,
                                               long long sBz, long long sCz) {
  __shared__ unsigned short As[128 * 32];
  __shared__ unsigned short Bs[128 * 32];
  const unsigned short* Bp = B + (size_t)blockIdx.z * sBz;
  int m0 = blockIdx.y * 128, n0 = blockIdx.x * 128;
  int tid = threadIdx.x;
  int w = tid >> 6, lane = tid & 63;
  int quad = lane >> 4, l15 = lane & 15;
  int wr = w >> 1, wc = w & 1;

  // staging chunks: c0 = tid, c1 = tid+256; row = c>>2, slot = c&3 holds global chunk slot^(row&3)
  int c0 = tid, c1 = tid + 256;
  int r0 = c0 >> 2, r1 = c1 >> 2;
  int cb0 = (c0 & 3) ^ (r0 & 3), cb1 = (c1 & 3) ^ (r1 & 3);
  const unsigned short* Ag0 = A + (size_t)(m0 + r0) * K + cb0 * 8;
  const unsigned short* Ag1 = A + (size_t)(m0 + r1) * K + cb1 * 8;
  const unsigned short* Bg0 = Bp + (size_t)(n0 + r0) * K + cb0 * 8;
  const unsigned short* Bg1 = Bp + (size_t)(n0 + r1) * K + cb1 * 8;

  f32x4 acc[4][4] = {};

  for (int kt = 0; kt < K / 32; kt++) {
    gload16(Ag0 + kt * 32, As + c0 * 8);
    gload16(Ag1 + kt * 32, As + c1 * 8);
    gload16(Bg0 + kt * 32, Bs + c0 * 8);
    gload16(Bg1 + kt * 32, Bs + c1 * 8);
    __syncthreads();
    bfrag af[4], bf_[4];
#pragma unroll
    for (int mt = 0; mt < 4; mt++) {
      int row = wr * 64 + mt * 16 + l15;
      int slot = quad ^ (row & 3);
      af[mt] = *(const bfrag*)(As + row * 32 + slot * 8);
    }
#pragma unroll
    for (int nt = 0; nt < 4; nt++) {
      int row = wc * 64 + nt * 16 + l15;
      int slot = quad ^ (row & 3);
      bf_[nt] = *(const bfrag*)(Bs + row * 32 + slot * 8);
    }
#pragma unroll
    for (int mt = 0; mt < 4; mt++)
#pragma unroll
      for (int nt = 0; nt < 4; nt++)
        acc[mt][nt] = __builtin_amdgcn_mfma_f32_16x16x32_bf16(af[mt], bf_[nt], acc[mt][nt], 0, 0, 0);
    __syncthreads();
  }

  int quad4 = quad * 4;
#pragma unroll
  for (int mt = 0; mt < 4; mt++) {
#pragma unroll
    for (int nt = 0; nt < 4; nt++) {
      int gm0 = m0 + wr * 64 + mt * 16 + quad4;
      int gn = n0 + wc * 64 + nt * 16 + l15;
      if constexpr (MODE == 0) {
        unsigned short* outb = (unsigned short*)Cout;
        float bv = bias[gn];
        int h = gn >> 6, d = gn & 63;
#pragma unroll
        for (int i = 0; i < 4; i++) {
          int gm = gm0 + i;
          int b = gm >> 11, s = gm & 2047;
          outb[((((size_t)b * NH + h) * S_LEN + s) << 6) + d] = f2bf(acc[mt][nt][i] + bv);
        }
      } else if constexpr (MODE == 1) {
        unsigned short* outb = (unsigned short*)Cout + (size_t)blockIdx.z * sCz;
#pragma unroll
        for (int i = 0; i < 4; i++) {
          int gm = gm0 + i;
          outb[(size_t)gm * N + gn] = f2bf(acc[mt][nt][i] + bias[gm]);
        }
      } else {
        float* outf = (float*)Cout;
        float bv = bias[gn];
#pragma unroll
        for (int i = 0; i < 4; i++) {
          int gm = gm0 + i;
          outf[(size_t)gm * N + gn] = acc[mt][nt][i] + bv;
        }
      }
    }
  }
}

// ---------------------------------------------------------------- fused attention
// Per block: one (b,h), 32 query rows. LDS: e[32][2048] bf16 (swizzled) + 2x 8KB stage
// + q[32][64] + l[32]. Computes e=exp(s/8) once, writes attn=e/l, PV on bf16 e, ctx=(e@v)/l.
__global__ __launch_bounds__(512, 1) void attn_kernel(const unsigned short* __restrict__ qh,
                                                      const unsigned short* __restrict__ kh,
                                                      const unsigned short* __restrict__ vt,
                                                      float* __restrict__ attn,
                                                      unsigned short* __restrict__ ctx) {
  extern __shared__ char smem[];
  unsigned short* e_sh = (unsigned short*)smem;              // 131072 B
  unsigned short* st0  = (unsigned short*)(smem + 131072);   // 8192 B
  unsigned short* st1  = (unsigned short*)(smem + 139264);   // 8192 B
  unsigned short* q_sh = (unsigned short*)(smem + 147456);   // 4096 B
  float* l_sh          = (float*)(smem + 151552);            // 128 B

  int tid = threadIdx.x;
  int w = tid >> 6, lane = tid & 63;
  int quad = lane >> 4, l15 = lane & 15;
  int mt = w >> 2, nt = w & 3;

  int bh = blockIdx.y;
  int b = bh >> 4, h = bh & 15;
  int q0 = blockIdx.x * 32;

  const unsigned short* qb = qh + ((size_t)bh * S_LEN + q0) * DEPTH;
  const unsigned short* kb = kh + (size_t)bh * S_LEN * DEPTH;
  const unsigned short* vb = vt + (size_t)b * D_MOD * S_LEN + (size_t)h * DEPTH * S_LEN;
  float* attn_b = attn + ((size_t)bh * S_LEN + q0) * S_LEN;

  if (tid < 32) l_sh[tid] = 0.f;

  int srow = tid >> 3;                    // staging row for 512x16B chunk pattern
  int scb = (tid & 7) ^ (srow & 7);       // swizzled global chunk

  if (tid < 256) {                        // q tile: 32 rows x 64 dims = 256 chunks
    int qr = tid >> 3, qcb = (tid & 7) ^ (qr & 7);
    gload16(qb + qr * DEPTH + qcb * 8, q_sh + tid * 8);
  }
  // stage k-tile 0 (64 k-rows x 64 dims)
  gload16(kb + srow * DEPTH + scb * 8, st0 + tid * 8);
  __syncthreads();

  // preload q A-fragments for this wave's mt
  bfrag aq[2];
#pragma unroll
  for (int kk = 0; kk < 2; kk++) {
    int row = mt * 16 + l15;
    int slot = (kk * 4 + quad) ^ (row & 7);
    aq[kk] = *(const bfrag*)(q_sh + row * 64 + slot * 8);
  }

  unsigned short* stbuf[2] = {st0, st1};
  float l_acc[4] = {0.f, 0.f, 0.f, 0.f};
  const float CEXP = 0.18033688011112042f;  // log2(e)/8

#pragma unroll 2
  for (int kt = 0; kt < 32; kt++) {
    unsigned short* cur = stbuf[kt & 1];
    if (kt + 1 < 32) {
      gload16(kb + ((kt + 1) * 64 + srow) * DEPTH + scb * 8, stbuf[(kt + 1) & 1] + tid * 8);
    } else {
      // prefetch v-tile 0 into st0 for the PV phase
      gload16(vb + (size_t)srow * S_LEN + scb * 8, st0 + tid * 8);
    }
    f32x4 acc = {0.f, 0.f, 0.f, 0.f};
#pragma unroll
    for (int kk = 0; kk < 2; kk++) {
      int row = nt * 16 + l15;
      int slot = (kk * 4 + quad) ^ (row & 7);
      bfrag bfr = *(const bfrag*)(cur + row * 64 + slot * 8);
      acc = __builtin_amdgcn_mfma_f32_16x16x32_bf16(aq[kk], bfr, acc, 0, 0, 0);
    }
    int cg = kt * 64 + nt * 16 + l15;     // global score column
    int cch = cg >> 3, coff = cg & 7;
#pragma unroll
    for (int i = 0; i < 4; i++) {
      int row = mt * 16 + quad * 4 + i;
      float e = fexp2(acc[i] * CEXP);
      l_acc[i] += e;
      int slot = cch ^ (row & 7);
      *(unsigned short*)((char*)e_sh + row * 4096 + slot * 16 + coff * 2) = f2bf(e);
    }
    __syncthreads();
  }

  // row-sum reduction: 16 lanes of each quad hold partials for the same rows
#pragma unroll
  for (int i = 0; i < 4; i++) {
    float v = l_acc[i];
    v += __shfl_xor(v, 1);
    v += __shfl_xor(v, 2);
    v += __shfl_xor(v, 4);
    v += __shfl_xor(v, 8);
    if (l15 == 0) atomicAdd(&l_sh[mt * 16 + quad * 4 + i], v);
  }
  __syncthreads();
  if (tid < 32) l_sh[tid] = 1.0f / l_sh[tid];
  __syncthreads();

  // PV phase, interleaved with attn row writes (overlaps HBM store with MFMA)
  f32x4 pacc = {0.f, 0.f, 0.f, 0.f};
#pragma unroll 2
  for (int t = 0; t < 32; t++) {
    unsigned short* cur = stbuf[t & 1];
    if (t + 1 < 32)
      gload16(vb + (size_t)srow * S_LEN + (t + 1) * 64 + scb * 8, stbuf[(t + 1) & 1] + tid * 8);
    // write attn row t: 512 threads x float4 = 2048 cols
    {
      float invl = l_sh[t];
      int col = tid * 4;
      int ch = col >> 3;
      int slot = ch ^ (t & 7);
      u16x4 ev = *(const u16x4*)((char*)e_sh + t * 4096 + slot * 16 + (col & 7) * 2);
      f32x4 o;
      o[0] = bf2f(ev[0]) * invl; o[1] = bf2f(ev[1]) * invl;
      o[2] = bf2f(ev[2]) * invl; o[3] = bf2f(ev[3]) * invl;
      *(f32x4*)(attn_b + (size_t)t * S_LEN + col) = o;
    }
#pragma unroll
    for (int kk = 0; kk < 2; kk++) {
      int arow = mt * 16 + l15;
      int ach = t * 8 + kk * 4 + quad;
      int aslot = ach ^ (arow & 7);
      bfrag af = *(const bfrag*)((char*)e_sh + arow * 4096 + aslot * 16);
      int brow = nt * 16 + l15;
      int bslot = (kk * 4 + quad) ^ (brow & 7);
      bfrag bf_ = *(const bfrag*)(cur + brow * 64 + bslot * 8);
      pacc = __builtin_amdgcn_mfma_f32_16x16x32_bf16(af, bf_, pacc, 0, 0, 0);
    }
    __syncthreads();
  }

  // ctx write: rows mt*16+quad*4+i, head-dim cols nt*16+l15; scale by 1/l
  int gd = h * 64 + nt * 16 + l15;
#pragma unroll
  for (int i = 0; i < 4; i++) {
    int r = mt * 16 + quad * 4 + i;
    float invl = l_sh[r];
    size_t gs = (size_t)b * S_LEN + q0 + r;
    ctx[gs * D_MOD + gd] = f2bf(pacc[i] * invl);
  }
}

// ---------------------------------------------------------------- launcher
extern "C" void kernel_launch(void* const* d_in, const int* in_sizes, int n_in,
                              void* d_out, int out_size, void* d_ws, size_t ws_size,
                              hipStream_t stream) {
  const float* Q  = (const float*)d_in[0];
  const float* K  = (const float*)d_in[1];
  const float* V  = (const float*)d_in[2];
  const float* WQ = (const float*)d_in[3];
  const float* bQ = (const float*)d_in[4];
  const float* WK = (const float*)d_in[5];
  const float* bK = (const float*)d_in[6];
  const float* WV = (const float*)d_in[7];
  const float* bV = (const float*)d_in[8];
  const float* WO = (const float*)d_in[9];
  const float* bO = (const float*)d_in[10];

  unsigned short* ws  = (unsigned short*)d_ws;
  unsigned short* X   = ws;                    // 8388608 elems (input cast; later ctx)
  unsigned short* WQt = ws + 8388608;
  unsigned short* WKt = WQt + 1048576;
  unsigned short* WVt = WKt + 1048576;
  unsigned short* WOt = WVt + 1048576;
  unsigned short* qh  = WOt + 1048576;         // [B,H,S,64] bf16
  unsigned short* kh  = qh + 8388608;          // [B,H,S,64] bf16
  unsigned short* vtb = kh + 8388608;          // [B, H*64, S] bf16 (v transposed)

  float* outp = (float*)d_out;
  float* attn = outp + (size_t)B_SZ * S_LEN * D_MOD;

  dim3 tb(32, 8), tg(32, 32);
  wtrans_kernel<<<tg, tb, 0, stream>>>(WQ, WQt);
  wtrans_kernel<<<tg, tb, 0, stream>>>(WK, WKt);
  wtrans_kernel<<<tg, tb, 0, stream>>>(WV, WVt);
  wtrans_kernel<<<tg, tb, 0, stream>>>(WO, WOt);

  int n8 = 8388608 / 8;
  dim3 cg(n8 / 256), cb(256);

  // Q projection -> qh (head-major)
  cast_kernel<<<cg, cb, 0, stream>>>(Q, X, n8);
  gemm_bt<0><<<dim3(8, 64, 1), 256, 0, stream>>>(X, WQt, bQ, (void*)qh, 1024, 1024, 0LL, 0LL);
  // K projection -> kh
  cast_kernel<<<cg, cb, 0, stream>>>(K, X, n8);
  gemm_bt<0><<<dim3(8, 64, 1), 256, 0, stream>>>(X, WKt, bK, (void*)kh, 1024, 1024, 0LL, 0LL);
  // V projection (transposed): vt[b][hd][s] = sum_k WVt[hd][k] * V[b][s][k] + bV[hd]
  cast_kernel<<<cg, cb, 0, stream>>>(V, X, n8);
  gemm_bt<1><<<dim3(16, 8, 4), 256, 0, stream>>>(WVt, X, bV, (void*)vtb, 2048, 1024,
                                                 (long long)S_LEN * D_MOD,
                                                 (long long)D_MOD * S_LEN);
  // fused attention: writes attn (d_out) + ctx (reuses X)
  hipFuncSetAttribute((const void*)attn_kernel, hipFuncAttributeMaxDynamicSharedMemorySize, 151680);
  attn_kernel<<<dim3(64, 64), 512, 151680, stream>>>(qh, kh, vtb, attn, X);
  // output projection -> d_out
  gemm_bt<2><<<dim3(8, 64, 1), 256, 0, stream>>>(X, WOt, bO, (void*)outp, 1024, 1024, 0LL, 0LL);
}